// Round 11
// baseline (123.668 us; speedup 1.0000x reference)
//
#include <hip/hip_runtime.h>
#include <hip/hip_bf16.h>
#include <cstdint>
#include <math.h>

// Shapes: B=256, P=128, K=512, HE=1024, HF=512 (2HF=1024), D=2560, HID=64
// Outputs: embeddings (256,1,1536) then weights (256,128), fp32, flat-concat.
//
// R18: wave specialization. R17's fused (~36.7 us) ran 5 serial phases at
//   2 waves/SIMD; proj GEMV (~5-7 us, 524 KB W1 from L2) sat serially before
//   the MFMA loop though its result is needed only at the fold. Now:
//   waves 0-3 = MFMA scores, 32 p-rows each (2 M-tiles, 8 MFMA/kk, dual
//   A-rings, keys-only vmcnt queue); waves 4-7 = proj GEMV concurrently
//   (512 d each, float4-over-h, W1-only queue). Each SIMD: 1 MFMA wave + 1
//   proj wave -> heterogeneous overlap (m114: co-scheduled waves = max, not
//   sum). A-prologue issued pre-barrier (independent of LDS repack).
//   Fold/softmax/ctx from R17 unchanged.
// Ledger (fused µs): R16 42.5 (rings deleted, VGPR=48) | R17 ~36.7
//   (launch_bounds(512,2) + G13 vectorize). Phase-sum floor ~17-20.
// Fixed harness overhead: ~81 µs of 256 MiB workspace-poison fills/iter.

typedef __bf16 bf16;
typedef __attribute__((ext_vector_type(8))) __bf16 bf16x8;
typedef __attribute__((ext_vector_type(4))) float f32x4;

#define NB 256
#define NP 128
#define NK 512
// LDS: sB 64K + sq 8K + aux 8K (proj-red 1K / ctx-cred 8K, time-disjoint)
//      + scores 512B + wts 512B
#define SMEM_BYTES (65536 + 8192 + 8192 + 512 + 512)

__global__ __launch_bounds__(512, 2) void fused_kernel(
    const float* __restrict__ keys, const float* __restrict__ query,
    const float* __restrict__ frame, const int* __restrict__ mask,
    const float* __restrict__ W1, const float* __restrict__ W2,
    float* __restrict__ out)
{
    extern __shared__ char smem[];
    char* sB      = smem;                          // 64 KB swizzled W1k bf16 [64][512]
    float* sq     = (float*)(smem + 65536);        // [2048] qf = query||frame
    float* aux    = sq + 2048;                     // [2048] red[4][64] / cred[4][512]
    float* scores = aux + 2048;                    // [128]
    float* wts    = scores + 128;                  // [128]

    const int b = blockIdx.x;
    const int t = threadIdx.x;
    const int w = t >> 6;              // wave 0..7
    const int lane = t & 63;
    const int m = lane & 15;
    const int q = lane >> 4;
    const int xorv = (m & 7) << 4;     // read-side swizzle (bits 4-6)

    // ---- phase 1: qf stage (2048 f32, one float4/thread, coalesced) ----
    {
        const int d = t * 4;
        const float* src = (d < 1024) ? (query + (size_t)b * 1024 + d)
                                      : (frame + (size_t)b * 1024 + (d - 1024));
        *(float4*)&sq[d] = *(const float4*)src;
    }

    // ---- phase 2: in-block repack W1[0:512][64] -> sB[h][k] bf16 swizzled ----
    {
#pragma unroll
        for (int i = 0; i < 8; i++) {
            const int id = t + 512 * i;         // 0..4095
            const int h = id & 63;
            const int kc = id >> 6;             // 0..63
            float v[8];
#pragma unroll
            for (int j = 0; j < 8; j++)
                v[j] = W1[(size_t)(kc * 8 + j) * 64 + h];
            bf16x8 bv;
#pragma unroll
            for (int j = 0; j < 8; j++) bv[j] = (bf16)v[j];
            *(bf16x8*)(sB + ((h * 1024 + kc * 16) ^ ((h & 7) << 4))) = bv;
        }
    }

    // ---- A prologue for MFMA waves (global loads independent of LDS;
    //      issued pre-barrier so they fly during the repack drain) ----
    const int p0 = (w & 3) * 32;       // MFMA waves: rows [p0, p0+32)
    const float* arow0 = keys + (size_t)b * (NP * NK) + (size_t)(p0 + m) * NK + q * 8;
    const float* arow1 = arow0 + 16 * NK;
    float4 A0a[4], A0b[4], A1a[4], A1b[4];
    if (w < 4) {
#pragma unroll
        for (int i = 0; i < 3; i++) {
            A0a[i] = *(const float4*)(arow0 + i * 32);
            A0b[i] = *(const float4*)(arow0 + i * 32 + 4);
            A1a[i] = *(const float4*)(arow1 + i * 32);
            A1b[i] = *(const float4*)(arow1 + i * 32 + 4);
        }
    }
    __syncthreads();

    if (w < 4) {
        // ================= MFMA scores: rows [p0, p0+32) =================
        f32x4 acc0[4], acc1[4];
#pragma unroll
        for (int nt = 0; nt < 4; nt++) {
            acc0[nt] = (f32x4){0.f, 0.f, 0.f, 0.f};
            acc1[nt] = (f32x4){0.f, 0.f, 0.f, 0.f};
        }
        bf16x8 Bp[2][4];
#pragma unroll
        for (int nt = 0; nt < 4; nt++)
            Bp[0][nt] = *(const bf16x8*)(sB + nt * 16384 + m * 1024 + ((q * 16) ^ xorv));

#pragma unroll
        for (int kk = 0; kk < 16; kk++) {        // full unroll -> static indices
            const int cur = kk & 3;
            const int bc = kk & 1;
            if (kk < 13) {                       // A rings: distance-3, keys-only queue
                A0a[(kk + 3) & 3] = *(const float4*)(arow0 + (kk + 3) * 32);
                A0b[(kk + 3) & 3] = *(const float4*)(arow0 + (kk + 3) * 32 + 4);
                A1a[(kk + 3) & 3] = *(const float4*)(arow1 + (kk + 3) * 32);
                A1b[(kk + 3) & 3] = *(const float4*)(arow1 + (kk + 3) * 32 + 4);
            }
            if (kk < 15) {                       // B: depth-1-ahead via lgkmcnt
#pragma unroll
                for (int nt = 0; nt < 4; nt++)
                    Bp[bc ^ 1][nt] = *(const bf16x8*)(sB + nt * 16384 + m * 1024
                                      + ((((kk + 1) * 64) | (q * 16)) ^ xorv));
            }
            bf16x8 Af0, Af1;
            Af0[0] = (bf16)A0a[cur].x; Af0[1] = (bf16)A0a[cur].y;
            Af0[2] = (bf16)A0a[cur].z; Af0[3] = (bf16)A0a[cur].w;
            Af0[4] = (bf16)A0b[cur].x; Af0[5] = (bf16)A0b[cur].y;
            Af0[6] = (bf16)A0b[cur].z; Af0[7] = (bf16)A0b[cur].w;
            Af1[0] = (bf16)A1a[cur].x; Af1[1] = (bf16)A1a[cur].y;
            Af1[2] = (bf16)A1a[cur].z; Af1[3] = (bf16)A1a[cur].w;
            Af1[4] = (bf16)A1b[cur].x; Af1[5] = (bf16)A1b[cur].y;
            Af1[6] = (bf16)A1b[cur].z; Af1[7] = (bf16)A1b[cur].w;
#pragma unroll
            for (int nt = 0; nt < 4; nt++) {
                acc0[nt] = __builtin_amdgcn_mfma_f32_16x16x32_bf16(Af0, Bp[bc][nt], acc0[nt], 0, 0, 0);
                acc1[nt] = __builtin_amdgcn_mfma_f32_16x16x32_bf16(Af1, Bp[bc][nt], acc1[nt], 0, 0, 0);
            }
        }
        __syncthreads();   // join with proj waves (red ready)

        // ---- fold: relu(acc + pv) * w2, reduce over 16 h-lanes ----
        float pr0[4] = {0.f, 0.f, 0.f, 0.f};
        float pr1[4] = {0.f, 0.f, 0.f, 0.f};
#pragma unroll
        for (int nt = 0; nt < 4; nt++) {
            const int h = nt * 16 + m;
            const float pvh = aux[h] + aux[64 + h] + aux[128 + h] + aux[192 + h];
            const float wvh = W2[h];
#pragma unroll
            for (int r = 0; r < 4; r++) {
                pr0[r] += fmaxf(acc0[nt][r] + pvh, 0.f) * wvh;
                pr1[r] += fmaxf(acc1[nt][r] + pvh, 0.f) * wvh;
            }
        }
#pragma unroll
        for (int off = 1; off < 16; off <<= 1)
#pragma unroll
            for (int r = 0; r < 4; r++) {
                pr0[r] += __shfl_xor(pr0[r], off);
                pr1[r] += __shfl_xor(pr1[r], off);
            }
        if (m == 0) {
#pragma unroll
            for (int r = 0; r < 4; r++) {
                scores[p0 + q * 4 + r] = pr0[r];
                scores[p0 + 16 + q * 4 + r] = pr1[r];
            }
        }
    } else {
        // ================= proj GEMV: wave owns 512 d-rows =================
        const int wp = w - 4;              // 0..3
        const int s4 = lane >> 4;          // sub-slice: 128 d-rows
        const int j = lane & 15;           // h-quad
        const int d0 = wp * 512 + s4 * 128;
        const float4* w1f4 = (const float4*)W1;
        float4 pa = {0.f, 0.f, 0.f, 0.f};
#pragma unroll
        for (int bt = 0; bt < 16; bt++) {
            float4 vv[8];
#pragma unroll
            for (int i = 0; i < 8; i++)
                vv[i] = w1f4[(size_t)(512 + d0 + bt * 8 + i) * 16 + j];
#pragma unroll
            for (int i = 0; i < 8; i++) {
                const float qv = sq[d0 + bt * 8 + i];
                pa.x += qv * vv[i].x; pa.y += qv * vv[i].y;
                pa.z += qv * vv[i].z; pa.w += qv * vv[i].w;
            }
        }
        // reduce over the 4 sub-slices (lanes xor 16, 32), write red[wp][h]
        pa.x += __shfl_xor(pa.x, 16); pa.y += __shfl_xor(pa.y, 16);
        pa.z += __shfl_xor(pa.z, 16); pa.w += __shfl_xor(pa.w, 16);
        pa.x += __shfl_xor(pa.x, 32); pa.y += __shfl_xor(pa.y, 32);
        pa.z += __shfl_xor(pa.z, 32); pa.w += __shfl_xor(pa.w, 32);
        if (lane < 16)
            *(float4*)&aux[wp * 64 + lane * 4] = pa;
        __syncthreads();   // join with MFMA waves
        // (fold handled by waves 0-3)
    }
    __syncthreads();

    // ---- ctx batch-0 prefetch hoisted above softmax ----
    const int cq = t & 127;
    const int pg = t >> 7;
    const float4* kp4 = (const float4*)(keys + (size_t)b * (NP * NK));
    float4 kv0[8];
#pragma unroll
    for (int i = 0; i < 8; i++)
        kv0[i] = kp4[(size_t)(pg * 32 + i) * 128 + cq];

    // ---- masked softmax over 128 scores (first 64 lanes), write weights ----
    if (t < 64) {
        const int pa_ = t, pb_ = t + 64;
        float s0 = (mask[b * 128 + pa_] == 0) ? -INFINITY : scores[pa_];
        float s1 = (mask[b * 128 + pb_] == 0) ? -INFINITY : scores[pb_];
        float mx = fmaxf(s0, s1);
#pragma unroll
        for (int off = 32; off; off >>= 1) mx = fmaxf(mx, __shfl_xor(mx, off));
        float e0 = __expf(s0 - mx), e1 = __expf(s1 - mx);
        float sum = e0 + e1;
#pragma unroll
        for (int off = 32; off; off >>= 1) sum += __shfl_xor(sum, off);
        const float inv = 1.0f / sum;
        e0 *= inv; e1 *= inv;
        wts[pa_] = e0; wts[pb_] = e1;
        float* wout = out + (size_t)NB * 1536;
        wout[b * 128 + pa_] = e0;
        wout[b * 128 + pb_] = e1;
    }
    __syncthreads();

    // ---- context: float4 cols, p-split x4, LDS combine ----
    {
        float4 ca = {0.f, 0.f, 0.f, 0.f};
#pragma unroll
        for (int i = 0; i < 8; i++) {
            const float wvv = wts[pg * 32 + i];
            ca.x += wvv * kv0[i].x; ca.y += wvv * kv0[i].y;
            ca.z += wvv * kv0[i].z; ca.w += wvv * kv0[i].w;
        }
#pragma unroll
        for (int bt = 1; bt < 4; bt++) {
            float4 kv[8];
#pragma unroll
            for (int i = 0; i < 8; i++)
                kv[i] = kp4[(size_t)(pg * 32 + bt * 8 + i) * 128 + cq];
#pragma unroll
            for (int i = 0; i < 8; i++) {
                const float wvv = wts[pg * 32 + bt * 8 + i];
                ca.x += wvv * kv[i].x; ca.y += wvv * kv[i].y;
                ca.z += wvv * kv[i].z; ca.w += wvv * kv[i].w;
            }
        }
        *(float4*)&aux[pg * 512 + cq * 4] = ca;   // cred[pg][col-quad]
    }
    __syncthreads();
    if (t < 512)
        out[(size_t)b * 1536 + t] =
            aux[t] + aux[512 + t] + aux[1024 + t] + aux[1536 + t];

    // ---- frame passthrough: embeddings[:, 512:1536] = frameLSTM_h ----
    if (t < 256) {
        const float4 fv = *(const float4*)(frame + (size_t)b * 1024 + t * 4);
        *(float4*)(out + (size_t)b * 1536 + 512 + t * 4) = fv;
    }
}

extern "C" void kernel_launch(void* const* d_in, const int* in_sizes, int n_in,
                              void* d_out, int out_size, void* d_ws, size_t ws_size,
                              hipStream_t stream) {
    const float* query = (const float*)d_in[0];
    const float* keys  = (const float*)d_in[1];
    const float* frame = (const float*)d_in[2];
    const int*   mask  = (const int*)d_in[3];
    const float* W1    = (const float*)d_in[4];
    const float* W2    = (const float*)d_in[5];
    float* out = (float*)d_out;

    hipFuncSetAttribute((const void*)fused_kernel,
                        hipFuncAttributeMaxDynamicSharedMemorySize, SMEM_BYTES);

    fused_kernel<<<256, 512, SMEM_BYTES, stream>>>(keys, query, frame, mask,
                                                   W1, W2, out);
}

// Round 12
// 123.397 us; speedup vs baseline: 1.0022x; 1.0022x over previous
//
#include <hip/hip_runtime.h>
#include <hip/hip_bf16.h>
#include <cstdint>
#include <math.h>

// Shapes: B=256, P=128, K=512, HE=1024, HF=512 (2HF=1024), D=2560, HID=64
// Outputs: embeddings (256,1,1536) then weights (256,128), fp32, flat-concat.
//
// R19: R18's wave specialization REGRESSED (+5 us): it halved the waves
//   issuing keys loads during the dominant keys phase. Revert to R17; fix
//   the keys A-feed instead: T14 LDS chunk pipeline, WAVE-PRIVATE buffers.
//   K = 8 chunks x 64 cols. Per chunk, per wave: issue 4 float4 loads for
//   c+1 (pre-swizzled global cols) -> ds_read+cvt+8 MFMA on c -> 4
//   ds_write_b128 of c+1 (linear dest). Wave-private bufs => NO barriers in
//   the loop; the load->ds_write->ds_read chain is memory-carried (compiler
//   can't sink/delete it, unlike the R16-deleted VGPR rings); staging holds
//   only 16 VGPRs. Read swizzle a^((m&7)<<4) (both-sides rule #21: source
//   pre-swizzled, read swizzled) => A-reads 2-way/free.
// Ledger (fused µs): R16 42.5 (rings deleted, VGPR=48) | R17 36.7 (vector
//   proj/ctx + launch_bounds(512,2)) | R18 ~42 (specialization REGRESSED).
//   Keys-phase est ~20 of R17's 36.7; HBM floor 10.4.
// Fixed harness overhead: ~81 µs of 256 MiB workspace-poison fills/iter.

typedef __bf16 bf16;
typedef __attribute__((ext_vector_type(8))) __bf16 bf16x8;
typedef __attribute__((ext_vector_type(4))) float f32x4;

#define NB 256
#define NP 128
#define NK 512
// LDS: sB 64K | sq 8K | aux 8K | scores 512B | wts 512B | kbuf 64K
#define SMEM_BYTES (65536 + 8192 + 8192 + 512 + 512 + 65536)   // 148480

__global__ __launch_bounds__(512, 2) void fused_kernel(
    const float* __restrict__ keys, const float* __restrict__ query,
    const float* __restrict__ frame, const int* __restrict__ mask,
    const float* __restrict__ W1, const float* __restrict__ W2,
    float* __restrict__ out)
{
    extern __shared__ char smem[];
    char* sB      = smem;                          // 64 KB swizzled W1k bf16 [64][512]
    float* sq     = (float*)(smem + 65536);        // [2048] qf = query||frame
    float* aux    = sq + 2048;                     // [2048] red[8][64] / cred[4][512]
    float* scores = aux + 2048;                    // [128]
    float* wts    = scores + 128;                  // [128]
    char* kb      = smem + 65536 + 8192 + 8192 + 1024;  // 64 KB keys chunk bufs

    const int b = blockIdx.x;
    const int t = threadIdx.x;
    const int w = t >> 6;              // wave 0..7
    const int lane = t & 63;
    const int m = lane & 15;
    const int q = lane >> 4;
    const int p0 = w * 16;             // wave's 16 p-rows
    const int xorv = (m & 7) << 4;     // read-side swizzle (bits 4-6)

    // ---- phase 1: qf stage (2048 f32, one float4/thread, coalesced) ----
    {
        const int d = t * 4;
        const float* src = (d < 1024) ? (query + (size_t)b * 1024 + d)
                                      : (frame + (size_t)b * 1024 + (d - 1024));
        *(float4*)&sq[d] = *(const float4*)src;
    }

    // ---- phase 2: in-block repack W1[0:512][64] -> sB[h][k] bf16 swizzled ----
    {
#pragma unroll
        for (int i = 0; i < 8; i++) {
            const int id = t + 512 * i;         // 0..4095
            const int h = id & 63;
            const int kc = id >> 6;             // 0..63
            float v[8];
#pragma unroll
            for (int j = 0; j < 8; j++)
                v[j] = W1[(size_t)(kc * 8 + j) * 64 + h];
            bf16x8 bv;
#pragma unroll
            for (int j = 0; j < 8; j++) bv[j] = (bf16)v[j];
            *(bf16x8*)(sB + ((h * 1024 + kc * 16) ^ ((h & 7) << 4))) = bv;
        }
    }

    // ---- keys chunk-0 issue (pre-barrier: flies during repack drain+proj).
    //      Pre-swizzled source col-chunk cc = c16 ^ (row&7)  [rule #21] ----
    const float* kbase = keys + (size_t)b * (NP * NK);
    float4 kvs[4];
#pragma unroll
    for (int s = 0; s < 4; s++) {
        const int rl = s * 4 + (lane >> 4);            // local row 0..15
        const int cc = (lane & 15) ^ (rl & 7);         // swizzled 16B col-chunk
        kvs[s] = *(const float4*)(kbase + (size_t)(p0 + rl) * NK + cc * 4);
    }
    __syncthreads();

    // ---- phase 3: proj GEMV, float4-over-h (R17) ----
    {
        const int s = t >> 4;          // 0..31: d-rows [64s, 64s+64)
        const int j = t & 15;          // h-quad
        const float4* w1f4 = (const float4*)W1;
        float4 pa = {0.f, 0.f, 0.f, 0.f};
#pragma unroll
        for (int bt = 0; bt < 8; bt++) {
            float4 vv[8];
#pragma unroll
            for (int i = 0; i < 8; i++)
                vv[i] = w1f4[(size_t)(512 + s * 64 + bt * 8 + i) * 16 + j];
#pragma unroll
            for (int i = 0; i < 8; i++) {
                const float qv = sq[s * 64 + bt * 8 + i];
                pa.x += qv * vv[i].x; pa.y += qv * vv[i].y;
                pa.z += qv * vv[i].z; pa.w += qv * vv[i].w;
            }
        }
        pa.x += __shfl_xor(pa.x, 16); pa.y += __shfl_xor(pa.y, 16);
        pa.z += __shfl_xor(pa.z, 16); pa.w += __shfl_xor(pa.w, 16);
        pa.x += __shfl_xor(pa.x, 32); pa.y += __shfl_xor(pa.y, 32);
        pa.z += __shfl_xor(pa.z, 32); pa.w += __shfl_xor(pa.w, 32);
        if (lane < 16)
            *(float4*)&aux[w * 64 + lane * 4] = pa;   // red[w][h=4j..4j+3]
    }
    __syncthreads();

    // ---- phase 4: fold constants; write chunk 0; Bp init ----
    float pv[4], wv[4];
#pragma unroll
    for (int nt = 0; nt < 4; nt++) {
        const int h = nt * 16 + m;
        float sacc = 0.f;
#pragma unroll
        for (int ww = 0; ww < 8; ww++) sacc += aux[ww * 64 + h];
        pv[nt] = sacc;
        wv[nt] = W2[h];
    }

    char* kbw = kb + w * 8192;         // wave-private region: 2 bufs x 4 KB
#pragma unroll
    for (int s = 0; s < 4; s++)
        *(float4*)(kbw + s * 1024 + lane * 16) = kvs[s];

    f32x4 acc[4];
#pragma unroll
    for (int nt = 0; nt < 4; nt++) acc[nt] = (f32x4){0.f, 0.f, 0.f, 0.f};

    bf16x8 Bp[2][4];
#pragma unroll
    for (int nt = 0; nt < 4; nt++)
        Bp[0][nt] = *(const bf16x8*)(sB + nt * 16384 + m * 1024 + ((q * 16) ^ xorv));

    // ---- phase 5: keys chunk loop — NO barriers (wave-private bufs) ----
#pragma unroll
    for (int c = 0; c < 8; c++) {      // full unroll -> static indices
        if (c < 7) {                   // issue next chunk's loads (T14 early)
#pragma unroll
            for (int s = 0; s < 4; s++) {
                const int rl = s * 4 + (lane >> 4);
                const int cc = (lane & 15) ^ (rl & 7);
                kvs[s] = *(const float4*)(kbase + (size_t)(p0 + rl) * NK
                                          + (c + 1) * 64 + cc * 4);
            }
        }
        const char* kbr = kbw + (c & 1) * 4096;
#pragma unroll
        for (int kk2 = 0; kk2 < 2; kk2++) {
            const int kkg = c * 2 + kk2;
            const int bc = kkg & 1;
            const int a0 = (m * 256 + kk2 * 128 + q * 32) ^ xorv;
            const float4 f0 = *(const float4*)(kbr + a0);
            const float4 f1 = *(const float4*)(kbr + (a0 ^ 16));
            if (kkg < 15) {            // B: depth-1-ahead via lgkmcnt
#pragma unroll
                for (int nt = 0; nt < 4; nt++)
                    Bp[bc ^ 1][nt] = *(const bf16x8*)(sB + nt * 16384 + m * 1024
                                      + ((((kkg + 1) * 64) | (q * 16)) ^ xorv));
            }
            bf16x8 Af;
            Af[0] = (bf16)f0.x; Af[1] = (bf16)f0.y;
            Af[2] = (bf16)f0.z; Af[3] = (bf16)f0.w;
            Af[4] = (bf16)f1.x; Af[5] = (bf16)f1.y;
            Af[6] = (bf16)f1.z; Af[7] = (bf16)f1.w;
#pragma unroll
            for (int nt = 0; nt < 4; nt++)
                acc[nt] = __builtin_amdgcn_mfma_f32_16x16x32_bf16(Af, Bp[bc][nt], acc[nt], 0, 0, 0);
        }
        if (c < 7) {                   // write next chunk (T14 late)
            char* kbwn = kbw + ((c + 1) & 1) * 4096;
#pragma unroll
            for (int s = 0; s < 4; s++)
                *(float4*)(kbwn + s * 1024 + lane * 16) = kvs[s];
        }
    }

    // fold 64 h-columns: relu(+proj) * w2, reduce over the 16 h-lanes
    float pr[4] = {0.f, 0.f, 0.f, 0.f};
#pragma unroll
    for (int nt = 0; nt < 4; nt++)
#pragma unroll
        for (int r = 0; r < 4; r++)
            pr[r] += fmaxf(acc[nt][r] + pv[nt], 0.f) * wv[nt];

#pragma unroll
    for (int off = 1; off < 16; off <<= 1)
#pragma unroll
        for (int r = 0; r < 4; r++)
            pr[r] += __shfl_xor(pr[r], off);

    if (m == 0) {
#pragma unroll
        for (int r = 0; r < 4; r++) scores[p0 + q * 4 + r] = pr[r];
    }
    __syncthreads();

    // ---- ctx batch-0 prefetch hoisted above softmax ----
    const int cq = t & 127;
    const int pg = t >> 7;
    const float4* kp4 = (const float4*)kbase;
    float4 kv0[8];
#pragma unroll
    for (int i = 0; i < 8; i++)
        kv0[i] = kp4[(size_t)(pg * 32 + i) * 128 + cq];

    // ---- masked softmax over 128 scores (first 64 lanes), write weights ----
    if (t < 64) {
        const int pa_ = t, pb_ = t + 64;
        float s0 = (mask[b * 128 + pa_] == 0) ? -INFINITY : scores[pa_];
        float s1 = (mask[b * 128 + pb_] == 0) ? -INFINITY : scores[pb_];
        float mx = fmaxf(s0, s1);
#pragma unroll
        for (int off = 32; off; off >>= 1) mx = fmaxf(mx, __shfl_xor(mx, off));
        float e0 = __expf(s0 - mx), e1 = __expf(s1 - mx);
        float sum = e0 + e1;
#pragma unroll
        for (int off = 32; off; off >>= 1) sum += __shfl_xor(sum, off);
        const float inv = 1.0f / sum;
        e0 *= inv; e1 *= inv;
        wts[pa_] = e0; wts[pb_] = e1;
        float* wout = out + (size_t)NB * 1536;
        wout[b * 128 + pa_] = e0;
        wout[b * 128 + pb_] = e1;
    }
    __syncthreads();

    // ---- context: float4 cols, p-split x4, LDS combine (R17) ----
    {
        float4 ca = {0.f, 0.f, 0.f, 0.f};
#pragma unroll
        for (int i = 0; i < 8; i++) {
            const float wvv = wts[pg * 32 + i];
            ca.x += wvv * kv0[i].x; ca.y += wvv * kv0[i].y;
            ca.z += wvv * kv0[i].z; ca.w += wvv * kv0[i].w;
        }
#pragma unroll
        for (int bt = 1; bt < 4; bt++) {
            float4 kv[8];
#pragma unroll
            for (int i = 0; i < 8; i++)
                kv[i] = kp4[(size_t)(pg * 32 + bt * 8 + i) * 128 + cq];
#pragma unroll
            for (int i = 0; i < 8; i++) {
                const float wvv = wts[pg * 32 + bt * 8 + i];
                ca.x += wvv * kv[i].x; ca.y += wvv * kv[i].y;
                ca.z += wvv * kv[i].z; ca.w += wvv * kv[i].w;
            }
        }
        *(float4*)&aux[pg * 512 + cq * 4] = ca;   // cred[pg][col-quad]
    }
    __syncthreads();
    if (t < 512)
        out[(size_t)b * 1536 + t] =
            aux[t] + aux[512 + t] + aux[1024 + t] + aux[1536 + t];

    // ---- frame passthrough: embeddings[:, 512:1536] = frameLSTM_h ----
    if (t < 256) {
        const float4 fv = *(const float4*)(frame + (size_t)b * 1024 + t * 4);
        *(float4*)(out + (size_t)b * 1536 + 512 + t * 4) = fv;
    }
}

extern "C" void kernel_launch(void* const* d_in, const int* in_sizes, int n_in,
                              void* d_out, int out_size, void* d_ws, size_t ws_size,
                              hipStream_t stream) {
    const float* query = (const float*)d_in[0];
    const float* keys  = (const float*)d_in[1];
    const float* frame = (const float*)d_in[2];
    const int*   mask  = (const int*)d_in[3];
    const float* W1    = (const float*)d_in[4];
    const float* W2    = (const float*)d_in[5];
    float* out = (float*)d_out;

    hipFuncSetAttribute((const void*)fused_kernel,
                        hipFuncAttributeMaxDynamicSharedMemorySize, SMEM_BYTES);

    fused_kernel<<<256, 512, SMEM_BYTES, stream>>>(keys, query, frame, mask,
                                                   W1, W2, out);
}

// Round 14
// 120.396 us; speedup vs baseline: 1.0272x; 1.0249x over previous
//
#include <hip/hip_runtime.h>
#include <hip/hip_bf16.h>
#include <cstdint>
#include <math.h>

// Shapes: B=256, P=128, K=512, HE=1024, HF=512 (2HF=1024), D=2560, HID=64
// Outputs: embeddings (256,1,1536) then weights (256,128), fp32, flat-concat.
//
// R21: async A-feed via __builtin_amdgcn_global_load_lds (zero asm; R20's
//   raw-asm variant core-dumped). Keys = 8 chunks x 64 cols; per chunk per
//   wave: 4 gload_lds (16B-wide) into a WAVE-PRIVATE 4KB double buffer.
//   The intrinsic is side-effecting -> compiler cannot sink/delete it
//   (kills the R16-R19 ring-deletion pathology). Source globals are
//   PRE-SWIZZLED (c16 ^ (row&7); rule #21 both-sides) so the swizzled
//   ds_read_b128 A-reads are 2-way/free. NO barriers in the loop (buffers
//   wave-private; compiler's waitcnt pass orders gload_lds->ds_read via
//   LDS aliasing). proj GEMV is folded INTO the chunk loop (slice c per
//   chunk): its vmcnt wait coincides with the stage wait -> proj absorbed
//   into keys BW time. Keys phase is pure BW (8 MFMA/chunk), so the
//   "drain" IS the BW floor here, not a tax.
// Ledger (fused µs): R16 42.5 | R17 36.7 (best) | R18 42 | R19 42 | R20
//   crash (asm). Keys HBM floor 10.4; fused floor ~18-20.
// Fixed harness overhead: ~81 µs of 256 MiB workspace-poison fills/iter.

typedef __bf16 bf16;
typedef __attribute__((ext_vector_type(8))) __bf16 bf16x8;
typedef __attribute__((ext_vector_type(4))) float f32x4;

#define NB 256
#define NP 128
#define NK 512
// LDS: sB 64K | kbuf 2x32K | sq 8K | aux 8K | scores 512B | wts 512B
#define SMEM_BYTES (65536 + 65536 + 8192 + 8192 + 512 + 512)   // 148480

// stage chunk C (64 f32 cols) for this wave into kbuf[PAR]; 4 x gload_lds.
// LDS layout per wave: row-major [16 rows][256 B], 16B-chunk c16 holds
// global chunk (c16 ^ (row&7))  [source-side of the read swizzle].
#define STAGE_CHUNK(C, PAR)                                                   \
    {                                                                         \
        _Pragma("unroll")                                                     \
        for (int i_ = 0; i_ < 4; i_++) {                                      \
            const int r4_ = p0 + i_ * 4 + (lane >> 4);                        \
            const int sc_ = (lane & 15) ^ (r4_ & 7);                          \
            const float* g_ = kbase + (size_t)r4_ * NK + (C) * 64 + sc_ * 4;  \
            char* l_ = kb + (PAR) * 32768 + w * 4096 + i_ * 1024;             \
            __builtin_amdgcn_global_load_lds(                                 \
                (const __attribute__((address_space(1))) uint32_t*)g_,        \
                (__attribute__((address_space(3))) uint32_t*)l_, 16, 0, 0);   \
        }                                                                     \
    }

__global__ __launch_bounds__(512, 2) void fused_kernel(
    const float* __restrict__ keys, const float* __restrict__ query,
    const float* __restrict__ frame, const int* __restrict__ mask,
    const float* __restrict__ W1, const float* __restrict__ W2,
    float* __restrict__ out)
{
    extern __shared__ char smem[];
    char* sB      = smem;                          // 64 KB swizzled W1k bf16 [64][512]
    char* kb      = smem + 65536;                  // 64 KB keys chunk bufs [2][8w][4K]
    float* sq     = (float*)(smem + 131072);       // [2048] qf = query||frame
    float* aux    = sq + 2048;                     // [2048] red[8][64] / cred[4][512]
    float* scores = aux + 2048;                    // [128]
    float* wts    = scores + 128;                  // [128]

    const int b = blockIdx.x;
    const int t = threadIdx.x;
    const int w = t >> 6;              // wave 0..7
    const int lane = t & 63;
    const int m = lane & 15;
    const int q = lane >> 4;
    const int p0 = w * 16;             // wave's 16 p-rows
    const int xorv = (m & 7) << 4;     // B read-side swizzle (bits 4-6)
    const float* kbase = keys + (size_t)b * (NP * NK);

    // ---- phase 1: qf stage (2048 f32, one float4/thread, coalesced) ----
    {
        const int d = t * 4;
        const float* src = (d < 1024) ? (query + (size_t)b * 1024 + d)
                                      : (frame + (size_t)b * 1024 + (d - 1024));
        *(float4*)&sq[d] = *(const float4*)src;
    }

    // ---- phase 2: in-block repack W1[0:512][64] -> sB[h][k] bf16 swizzled ----
    {
#pragma unroll
        for (int i = 0; i < 8; i++) {
            const int id = t + 512 * i;         // 0..4095
            const int h = id & 63;
            const int kc = id >> 6;             // 0..63
            float v[8];
#pragma unroll
            for (int j = 0; j < 8; j++)
                v[j] = W1[(size_t)(kc * 8 + j) * 64 + h];
            bf16x8 bv;
#pragma unroll
            for (int j = 0; j < 8; j++) bv[j] = (bf16)v[j];
            *(bf16x8*)(sB + ((h * 1024 + kc * 16) ^ ((h & 7) << 4))) = bv;
        }
    }

    // ---- stage chunk 0 (flies during the repack barrier drain) ----
    STAGE_CHUNK(0, 0);
    __syncthreads();    // sB/sq ready; drains chunk-0 loads too

    // ---- phase 3: fused keys-MFMA + proj chunk loop (NO in-loop barriers) ----
    const int s5 = t >> 4;             // proj d-slice 0..31 (8 rows/chunk)
    const int jq = t & 15;             // proj h-quad
    const float4* w1f4 = (const float4*)W1;
    float4 pa4 = {0.f, 0.f, 0.f, 0.f};

    f32x4 acc[4];
#pragma unroll
    for (int nt = 0; nt < 4; nt++) acc[nt] = (f32x4){0.f, 0.f, 0.f, 0.f};

#pragma unroll
    for (int c = 0; c < 8; c++) {      // full unroll -> static indices
        // --- MFMA on chunk c from kbuf[c&1] (wave-private) ---
        const char* kbr = kb + (c & 1) * 32768 + w * 4096;
#pragma unroll
        for (int kk2 = 0; kk2 < 2; kk2++) {
            const int kkg = c * 2 + kk2;
            const int a0 = m * 256 + ((kk2 * 128 + q * 32) ^ xorv);
            const float4 f0 = *(const float4*)(kbr + a0);
            const float4 f1 = *(const float4*)(kbr + (a0 ^ 16));
            bf16x8 Af;
            Af[0] = (bf16)f0.x; Af[1] = (bf16)f0.y;
            Af[2] = (bf16)f0.z; Af[3] = (bf16)f0.w;
            Af[4] = (bf16)f1.x; Af[5] = (bf16)f1.y;
            Af[6] = (bf16)f1.z; Af[7] = (bf16)f1.w;
#pragma unroll
            for (int nt = 0; nt < 4; nt++) {
                const bf16x8 Bf = *(const bf16x8*)(sB + nt * 16384 + m * 1024
                                   + (((kkg * 64) | (q * 16)) ^ xorv));
                acc[nt] = __builtin_amdgcn_mfma_f32_16x16x32_bf16(Af, Bf, acc[nt], 0, 0, 0);
            }
        }
        // --- stage chunk c+1 (async; lands before next iter's ds_read) ---
        if (c < 7) STAGE_CHUNK(c + 1, (c + 1) & 1);
        // --- proj slice c: 8 d-rows; its vmcnt wait absorbs the stage wait ---
        {
            const int d0 = c * 256 + s5 * 8;
            float4 vv[8];
#pragma unroll
            for (int i = 0; i < 8; i++)
                vv[i] = w1f4[(size_t)(512 + d0 + i) * 16 + jq];
#pragma unroll
            for (int i = 0; i < 8; i++) {
                const float qv = sq[d0 + i];
                pa4.x += qv * vv[i].x; pa4.y += qv * vv[i].y;
                pa4.z += qv * vv[i].z; pa4.w += qv * vv[i].w;
            }
        }
    }

    // ---- proj reduce: over the wave's 4 d-slices, then cross-wave via aux ----
    pa4.x += __shfl_xor(pa4.x, 16); pa4.y += __shfl_xor(pa4.y, 16);
    pa4.z += __shfl_xor(pa4.z, 16); pa4.w += __shfl_xor(pa4.w, 16);
    pa4.x += __shfl_xor(pa4.x, 32); pa4.y += __shfl_xor(pa4.y, 32);
    pa4.z += __shfl_xor(pa4.z, 32); pa4.w += __shfl_xor(pa4.w, 32);
    if (lane < 16)
        *(float4*)&aux[w * 64 + lane * 4] = pa4;   // red[w][h=4jq..4jq+3]
    __syncthreads();

    // ---- fold 64 h-columns: relu(acc + pv) * w2, reduce over 16 h-lanes ----
    float pr[4] = {0.f, 0.f, 0.f, 0.f};
#pragma unroll
    for (int nt = 0; nt < 4; nt++) {
        const int h = nt * 16 + m;
        float pvh = 0.f;
#pragma unroll
        for (int ww = 0; ww < 8; ww++) pvh += aux[ww * 64 + h];
        const float wvh = W2[h];
#pragma unroll
        for (int r = 0; r < 4; r++)
            pr[r] += fmaxf(acc[nt][r] + pvh, 0.f) * wvh;
    }
#pragma unroll
    for (int off = 1; off < 16; off <<= 1)
#pragma unroll
        for (int r = 0; r < 4; r++)
            pr[r] += __shfl_xor(pr[r], off);

    if (m == 0) {
#pragma unroll
        for (int r = 0; r < 4; r++) scores[p0 + q * 4 + r] = pr[r];
    }
    __syncthreads();

    // ---- ctx batch-0 prefetch hoisted above softmax ----
    const int cq = t & 127;
    const int pg = t >> 7;
    const float4* kp4 = (const float4*)kbase;
    float4 kv0[8];
#pragma unroll
    for (int i = 0; i < 8; i++)
        kv0[i] = kp4[(size_t)(pg * 32 + i) * 128 + cq];

    // ---- masked softmax over 128 scores (first 64 lanes), write weights ----
    if (t < 64) {
        const int pa_ = t, pb_ = t + 64;
        float s0 = (mask[b * 128 + pa_] == 0) ? -INFINITY : scores[pa_];
        float s1 = (mask[b * 128 + pb_] == 0) ? -INFINITY : scores[pb_];
        float mx = fmaxf(s0, s1);
#pragma unroll
        for (int off = 32; off; off >>= 1) mx = fmaxf(mx, __shfl_xor(mx, off));
        float e0 = __expf(s0 - mx), e1 = __expf(s1 - mx);
        float sum = e0 + e1;
#pragma unroll
        for (int off = 32; off; off >>= 1) sum += __shfl_xor(sum, off);
        const float inv = 1.0f / sum;
        e0 *= inv; e1 *= inv;
        wts[pa_] = e0; wts[pb_] = e1;
        float* wout = out + (size_t)NB * 1536;
        wout[b * 128 + pa_] = e0;
        wout[b * 128 + pb_] = e1;
    }
    __syncthreads();

    // ---- context: float4 cols, p-split x4, LDS combine ----
    {
        float4 ca = {0.f, 0.f, 0.f, 0.f};
#pragma unroll
        for (int i = 0; i < 8; i++) {
            const float wvv = wts[pg * 32 + i];
            ca.x += wvv * kv0[i].x; ca.y += wvv * kv0[i].y;
            ca.z += wvv * kv0[i].z; ca.w += wvv * kv0[i].w;
        }
#pragma unroll
        for (int bt = 1; bt < 4; bt++) {
            float4 kv[8];
#pragma unroll
            for (int i = 0; i < 8; i++)
                kv[i] = kp4[(size_t)(pg * 32 + bt * 8 + i) * 128 + cq];
#pragma unroll
            for (int i = 0; i < 8; i++) {
                const float wvv = wts[pg * 32 + bt * 8 + i];
                ca.x += wvv * kv[i].x; ca.y += wvv * kv[i].y;
                ca.z += wvv * kv[i].z; ca.w += wvv * kv[i].w;
            }
        }
        *(float4*)&aux[pg * 512 + cq * 4] = ca;   // cred[pg][col-quad]
    }
    __syncthreads();
    if (t < 512)
        out[(size_t)b * 1536 + t] =
            aux[t] + aux[512 + t] + aux[1024 + t] + aux[1536 + t];

    // ---- frame passthrough: embeddings[:, 512:1536] = frameLSTM_h ----
    if (t < 256) {
        const float4 fv = *(const float4*)(frame + (size_t)b * 1024 + t * 4);
        *(float4*)(out + (size_t)b * 1536 + 512 + t * 4) = fv;
    }
}

extern "C" void kernel_launch(void* const* d_in, const int* in_sizes, int n_in,
                              void* d_out, int out_size, void* d_ws, size_t ws_size,
                              hipStream_t stream) {
    const float* query = (const float*)d_in[0];
    const float* keys  = (const float*)d_in[1];
    const float* frame = (const float*)d_in[2];
    const int*   mask  = (const int*)d_in[3];
    const float* W1    = (const float*)d_in[4];
    const float* W2    = (const float*)d_in[5];
    float* out = (float*)d_out;

    hipFuncSetAttribute((const void*)fused_kernel,
                        hipFuncAttributeMaxDynamicSharedMemorySize, SMEM_BYTES);

    fused_kernel<<<256, 512, SMEM_BYTES, stream>>>(keys, query, frame, mask,
                                                   W1, W2, out);
}